// Round 2
// baseline (1320.950 us; speedup 1.0000x reference)
//
#include <hip/hip_runtime.h>
#include <hip/hip_fp16.h>

// Literal replication of the reference:
//   X = rfft(x, n=163839); H = rfft(h, n=163839); y = irfft(X*H)[:131072]
// N1=163839, N2=163838 -> Bluestein on L=2^18; four-step 512x512.
// R5: fp16 stored intermediates, fp32 register math.
// R6: 16-column tiles (512-thr blocks) -> 64B global segments (fetch granularity
//     fix); conflict-free LDS strides (514 half2 / 257 float); zero-upper-half
//     FFT specialization for REAL/COMBINE; hoisted cross-lane twiddles with
//     uniform cmul stages; COMBINE rescale folded into Hc at EXTRACT.

#define L1FFT 262144
#define NCHAN 128
#define CN1 163839LL
#define CN2 163838LL
#define MBINS 81920
#define XLEN 131072
#define HLEN 32768
#define TWO_PI 6.28318530717958647692f
#define INV512T (1.0f/512.0f)
#define INVLT   (1.0f/262144.0f)
#define CHIRP12 ((float)(0.5 / (163839.0 * 163838.0)))   // turns per k^2

#define CM_BUILD   0
#define CM_REAL    1
#define CM_COMBINE 2
#define CM_EXTRACT 3
#define CM_FINAL   4
#define RM_BUILD   0
#define RM_CONV    1

// half2 tile column stride: 514 % 32 == 2 -> all maps conflict-free or 2-way(free)
#define TS  514
// float stride for CM_FINAL (257 % 32 == 1, only 256 rows needed)
#define TFS 257

__device__ __forceinline__ float2 cmulf(float2 a, float2 b) {
  return make_float2(a.x*b.x - a.y*b.y, a.x*b.y + a.y*b.x);
}
__device__ __forceinline__ float2 cmulcf(float2 a, float2 b) {  // a * conj(b)
  return make_float2(a.x*b.x + a.y*b.y, a.y*b.x - a.x*b.y);
}
__device__ __forceinline__ float2 caddf(float2 a, float2 b){ return make_float2(a.x+b.x, a.y+b.y); }
__device__ __forceinline__ float2 csubf(float2 a, float2 b){ return make_float2(a.x-b.x, a.y-b.y); }

// e^{i*2pi*t} — native HW sin/cos take revolutions (v_sin_f32: sin(S0*2pi))
__device__ __forceinline__ float2 sc_turn(float t) {
  return make_float2(__builtin_amdgcn_cosf(t), __builtin_amdgcn_sinf(t));
}

// e^{sgn*i*pi*n^2/N1}: exact int64 mod by compile-time 2*N1, then turns
__device__ __forceinline__ float2 chirp1(float sgn, long long n) {
  long long m = (n*n) % (2*CN1);
  return sc_turn(sgn * (float)m * (1.0f/(float)(2*CN1)));
}
// e^{sgn*i*pi*n^2/N2}
__device__ __forceinline__ float2 chirp2(float sgn, long long n) {
  long long m = (n*n) % (2*CN2);
  return sc_turn(sgn * (float)m * (1.0f/(float)(2*CN2)));
}
// generic (runtime Q) — only used by the tiny BUILD dispatches
__device__ __forceinline__ float2 chirpv(float sgn, long long Q, long long n) {
  long long m = (n*n) % (2*Q);
  float ang = sgn * (0.5f*TWO_PI) * (float)m / (float)Q;
  float s, c; __sincosf(ang, &s, &c);
  return make_float2(c, s);
}

__device__ __forceinline__ int brev4(int x) {
  return ((x&1)<<3) | ((x&2)<<1) | ((x&4)>>1) | ((x&8)>>3);
}
__device__ __forceinline__ int brev5(int x) {
  return (int)(__brev((unsigned)x) >> 27);
}
__device__ __forceinline__ float2 shflx(float2 a, int m) {
  return make_float2(__shfl_xor(a.x, m, 64), __shfl_xor(a.y, m, 64));
}

#define C16_1 0.9238795325f
#define C16_2 0.7071067812f
#define C16_3 0.3826834324f
__device__ __forceinline__ float c16t(int j) {
  const float C[8] = {1.f, C16_1, C16_2, C16_3, 0.f, -C16_3, -C16_2, -C16_1};
  return C[j];
}
__device__ __forceinline__ float s16t(int j) {
  const float S[8] = {0.f, C16_3, C16_2, C16_1, 1.f, C16_1, C16_2, C16_3};
  return S[j];
}

// ---- in-lane 16-point DIF, stages 2..4 (shared) ----
__device__ __forceinline__ void lane16_fwd_rest(float2 v[16], float dsg) {
  #pragma unroll
  for (int h = 0; h < 2; ++h)
    #pragma unroll
    for (int j = 0; j < 4; ++j) {
      int i0 = h*8 + j;
      float wr = c16t(2*j), wi = dsg * s16t(2*j);
      float2 a = v[i0], b = v[i0+4];
      v[i0] = caddf(a, b);
      float2 tt = csubf(a, b);
      v[i0+4] = make_float2(tt.x*wr - tt.y*wi, tt.x*wi + tt.y*wr);
    }
  #pragma unroll
  for (int q = 0; q < 4; ++q)
    #pragma unroll
    for (int j = 0; j < 2; ++j) {
      int i0 = q*4 + j;
      float2 a = v[i0], b = v[i0+2];
      v[i0] = caddf(a, b);
      float2 tt = csubf(a, b);
      v[i0+2] = (j == 0) ? tt : make_float2(-dsg*tt.y, dsg*tt.x);
    }
  #pragma unroll
  for (int p = 0; p < 8; ++p) {
    float2 a = v[2*p], b = v[2*p+1];
    v[2*p] = caddf(a, b);
    v[2*p+1] = csubf(a, b);
  }
}
// dense input
__device__ __forceinline__ void lane16_fwd(float2 v[16], float dsg) {
  #pragma unroll
  for (int j = 0; j < 8; ++j) {
    float wr = c16t(j), wi = dsg * s16t(j);
    float2 a = v[j], b = v[j+8];
    v[j] = caddf(a, b);
    float2 tt = csubf(a, b);
    v[j+8] = make_float2(tt.x*wr - tt.y*wi, tt.x*wi + tt.y*wr);
  }
  lane16_fwd_rest(v, dsg);
}
// v[8..15] known zero on entry (not read): stage 1 degenerates to v[j+8]=v[j]*w
__device__ __forceinline__ void lane16_fwd_h0(float2 v[16], float dsg) {
  #pragma unroll
  for (int j = 0; j < 8; ++j) {
    float wr = c16t(j), wi = dsg * s16t(j);
    float2 a = v[j];
    v[j+8] = make_float2(a.x*wr - a.y*wi, a.x*wi + a.y*wr);
  }
  lane16_fwd_rest(v, dsg);
}

// ---- in-lane 16-point inverse-mirror ----
__device__ __forceinline__ void lane16_inv(float2 v[16], float dsg) {
  #pragma unroll
  for (int p = 0; p < 8; ++p) {
    float2 a = v[2*p], b = v[2*p+1];
    v[2*p] = caddf(a, b);
    v[2*p+1] = csubf(a, b);
  }
  #pragma unroll
  for (int q = 0; q < 4; ++q)
    #pragma unroll
    for (int j = 0; j < 2; ++j) {
      int i0 = q*4 + j;
      float2 a = v[i0], b = v[i0+2];
      float2 tb = (j == 0) ? b : make_float2(dsg*b.y, -dsg*b.x);
      v[i0] = caddf(a, tb);
      v[i0+2] = csubf(a, tb);
    }
  #pragma unroll
  for (int h = 0; h < 2; ++h)
    #pragma unroll
    for (int j = 0; j < 4; ++j) {
      int i0 = h*8 + j;
      float wr = c16t(2*j), wi = dsg * s16t(2*j);
      float2 a = v[i0], b = v[i0+4];
      float2 tb = make_float2(b.x*wr + b.y*wi, b.y*wr - b.x*wi);
      v[i0] = caddf(a, tb);
      v[i0+4] = csubf(a, tb);
    }
  #pragma unroll
  for (int j = 0; j < 8; ++j) {
    float wr = c16t(j), wi = dsg * s16t(j);
    float2 a = v[j], b = v[j+8];
    float2 tb = make_float2(b.x*wr + b.y*wi, b.y*wr - b.x*wi);
    v[j] = caddf(a, tb);
    v[j+8] = csubf(a, tb);
  }
}

// Per-lane cross-stage twiddles, hi-lane-selected once (low lanes get 1+0i so
// the stage body is a uniform cmul — no per-reg cndmask).
struct WSel { float2 a16, a8, a4, a2; };
__device__ __forceinline__ WSel make_wsel(int l, float dsg) {
  const float2 one = make_float2(1.f, 0.f);
  WSel w;
  w.a16 = (l & 16) ? sc_turn(dsg * (1.0f/32.0f) * (float)(l & 15)) : one;
  w.a8  = (l & 8)  ? sc_turn(dsg * (1.0f/16.0f) * (float)(l & 7))  : one;
  w.a4  = (l & 4)  ? sc_turn(dsg * (1.0f/8.0f)  * (float)(l & 3))  : one;
  w.a2  = ((l & 2) && (l & 1)) ? make_float2(0.f, dsg) : one;
  return w;
}

#define XF(mask, w) {                                                          \
    bool hi = (l & (mask)) != 0;                                               \
    _Pragma("unroll")                                                          \
    for (int r = 0; r < 16; ++r) {                                             \
      float2 o = shflx(v[r], (mask));                                          \
      float2 d = hi ? csubf(o, v[r]) : caddf(v[r], o);                         \
      v[r] = cmulf(d, (w));                                                    \
    } }
#define XFP(mask) {                                                            \
    bool hi = (l & (mask)) != 0;                                               \
    _Pragma("unroll")                                                          \
    for (int r = 0; r < 16; ++r) {                                             \
      float2 o = shflx(v[r], (mask));                                          \
      v[r] = hi ? csubf(o, v[r]) : caddf(v[r], o);                             \
    } }
#define XI(mask, w) {                                                          \
    bool hi = (l & (mask)) != 0;                                               \
    _Pragma("unroll")                                                          \
    for (int r = 0; r < 16; ++r) {                                             \
      float2 b = cmulcf(v[r], (w));                                            \
      float2 o = shflx(b, (mask));                                             \
      v[r] = hi ? csubf(o, b) : caddf(b, o);                                   \
    } }
#define XIP(mask) {                                                            \
    bool hi = (l & (mask)) != 0;                                               \
    _Pragma("unroll")                                                          \
    for (int r = 0; r < 16; ++r) {                                             \
      float2 b = v[r];                                                         \
      float2 o = shflx(b, (mask));                                             \
      v[r] = hi ? csubf(o, b) : caddf(b, o);                                   \
    } }

// Full 512-pt forward: input lane l reg m = x[l+32m];
// output lane l reg r = X[brev4(r) + 16*brev5(l)].
__device__ __forceinline__ void fft512_core_fwd(float2 v[16], int l, float dsg,
                                                const WSel& w) {
  #pragma unroll
  for (int r = 1; r < 16; ++r)                // W512^{l*brev4(r)} — exact turns
    v[r] = cmulf(v[r], sc_turn(dsg * INV512T * (float)(l * brev4(r))));
  XF(16, w.a16); XF(8, w.a8); XF(4, w.a4); XF(2, w.a2); XFP(1);
}
__device__ __forceinline__ void fft512_fwd(float2 v[16], int l, float dsg,
                                           const WSel& w) {
  lane16_fwd(v, dsg);
  fft512_core_fwd(v, l, dsg, w);
}
__device__ __forceinline__ void fft512_fwd_h0(float2 v[16], int l, float dsg,
                                              const WSel& w) {
  lane16_fwd_h0(v, dsg);
  fft512_core_fwd(v, l, dsg, w);
}

// Unnormalized inverse (x512) of fft512_fwd(dsg)
__device__ __forceinline__ void fft512_inv(float2 v[16], int l, float dsg,
                                           const WSel& w) {
  XIP(1); XI(2, w.a2); XI(4, w.a4); XI(8, w.a8); XI(16, w.a16);
  #pragma unroll
  for (int r = 1; r < 16; ++r)
    v[r] = cmulf(v[r], sc_turn(-dsg * INV512T * (float)(l * brev4(r))));
  lane16_inv(v, dsg);
}

// ---------------- column pass (512 threads, 16 columns/block) ----------------
__global__ __launch_bounds__(512) void pass_col_k(
    int mode,
    const float* __restrict__ realSrc, int realLen,
    const __half2* cplxSrc,
    const __half2* __restrict__ hcIn,
    __half2* dstFull,
    __half2* __restrict__ specOut,
    float* __restrict__ realOut,
    long long Q, float csgn, int lo, int hi)
{
  // half2 tile: 16 cols * 514 = 32896 B; FINAL aliases float 16*257*4 = 16448 B
  __shared__ __align__(16) unsigned char ldsraw[16 * TS * 4];
  __half2* tile = (__half2*)ldsraw;
  const int t   = threadIdx.x;
  const int c0  = blockIdx.x * 16;
  const int ch  = blockIdx.y;
  const int l   = t & 31;
  const int ccf = t >> 5;
  const int c   = c0 + ccf;
  float2 v[16];
  WSel ws = make_wsel(l, -1.f);

  if (mode == CM_BUILD) {
    #pragma unroll
    for (int m = 0; m < 16; ++m) {
      int n = ((l + 32*m) << 9) + c;
      int np = (n <= hi) ? n : n - L1FFT;
      v[m] = (np >= lo) ? chirpv(csgn, Q, (long long)np) : make_float2(0.f, 0.f);
    }
  } else if (mode == CM_REAL) {
    // input rows >= 256 are zero (realLen <= 131072) — stage rows < 256 only
    #pragma unroll
    for (int i = 0; i < 8; ++i) {
      int qq = t + 512*i;
      int cc = qq & 15, r = qq >> 4;          // r < 256
      int n = (r << 9) + c0 + cc;
      float2 val = make_float2(0.f, 0.f);
      if (n < realLen) {
        float xv = realSrc[(size_t)ch * realLen + n];
        float2 cw = chirp1(-1.f, (long long)n);        // pre-chirp
        val = make_float2(xv*cw.x, xv*cw.y);
      }
      tile[cc*TS + r] = __float22half2_rn(val);
    }
    __syncthreads();
    #pragma unroll
    for (int m = 0; m < 8; ++m) v[m] = __half22float2(tile[ccf*TS + l + 32*m]);
    __syncthreads();
  } else {
    #pragma unroll
    for (int i = 0; i < 16; ++i) {
      int qq = t + 512*i;
      int cc = qq & 15, z = qq >> 4;
      int la = z & 31, ra = z >> 5;
      int j = brev4(ra) + 16*brev5(la);
      tile[cc*TS + la + 32*ra] = cplxSrc[(size_t)ch*L1FFT + (j << 9) + c0 + cc];
    }
    __syncthreads();
    #pragma unroll
    for (int m = 0; m < 16; ++m) v[m] = __half22float2(tile[ccf*TS + l + 32*m]);
    __syncthreads();
  }

  if (mode == CM_COMBINE) {
    fft512_inv(v, l, -1.f, ws);     // completes X's Bluestein conv
    #pragma unroll
    for (int m = 0; m <= 4; ++m) {  // n < 160 <=> k < MBINS
      int n = l + 32*m;
      // Hc already carries postchirp1*prechirp2*eps/CN2 (folded at EXTRACT)
      float2 H = __half22float2(hcIn[(size_t)ch*MBINS + c*160 + n]);
      v[m] = cmulf(v[m], H);
    }
    #pragma unroll
    for (int m = 5; m < 8; ++m) v[m] = make_float2(0.f, 0.f);
  }

  if (mode <= CM_COMBINE) {         // BUILD / REAL / COMBINE: fwd FFT + store
    if (mode == CM_BUILD) fft512_fwd(v, l, -1.f, ws);
    else                  fft512_fwd_h0(v, l, -1.f, ws);  // upper half zero
    #pragma unroll
    for (int r = 0; r < 16; ++r) {  // four-step twiddle (exact turns) + slot write
      int k1 = brev4(r), k2 = brev5(l);
      int kf = k1 + 16*k2;
      float2 w = sc_turn(-INVLT * (float)(c * kf));
      tile[ccf*TS + k2 + 32*k1] = __float22half2_rn(cmulf(v[r], w));
    }
    __syncthreads();
    {
      int cc = t & 15, u = t >> 4;
      #pragma unroll
      for (int i = 0; i < 16; ++i)
        dstFull[(size_t)ch*L1FFT + ((i + 16*u) << 9) + c0 + cc] =
            tile[cc*TS + u + 32*i];
    }
  } else if (mode == CM_EXTRACT) {
    fft512_inv(v, l, -1.f, ws);
    #pragma unroll
    for (int m = 0; m <= 4; ++m) {
      int n = l + 32*m;
      long long k = ((long long)n << 9) + c;
      float2 cw = chirp1(-1.f, k);                 // postchirp of conv1
      float fk = (float)k;
      float2 wc = sc_turn(fk * fk * CHIRP12);      // rechirp for conv2 (N1-N2=1)
      float eps = (k == 0 || k == MBINS-1) ? 1.f : 2.f;
      float sc = eps / (float)CN2;
      float2 cw2 = cmulf(cw, wc);
      cw2 = make_float2(cw2.x*sc, cw2.y*sc);
      specOut[(size_t)ch*MBINS + c*160 + n] = __float22half2_rn(cmulf(v[m], cw2));
    }
  } else {                          // CM_FINAL
    fft512_inv(v, l, -1.f, ws);
    float* tf = (float*)ldsraw;
    #pragma unroll
    for (int m = 0; m < 8; ++m) {
      int n = l + 32*m;
      long long nb = ((long long)n << 9) + c;
      float2 cw = chirp2(+1.f, nb);
      tf[ccf*TFS + n] = v[m].x*cw.x - v[m].y*cw.y;
    }
    __syncthreads();
    {
      int cc = t & 15, u = t >> 4;
      #pragma unroll
      for (int i = 0; i < 8; ++i) {
        int n = u + 32*i;
        realOut[(size_t)ch*XLEN + (n << 9) + c0 + cc] = tf[cc*TFS + n];
      }
    }
  }
}

// ---------------- row pass (LDS-free, 256 threads) ----------------
__global__ __launch_bounds__(256) void pass_row_k(
    int mode, __half2* a, const __half2* __restrict__ g)
{
  const int t = threadIdx.x;
  const int l = t & 31;
  const int row = blockIdx.x * 8 + (t >> 5);
  const int ch = blockIdx.y;
  __half2* A = a + (size_t)ch * L1FFT + (size_t)row * 512;
  float2 v[16];
  WSel ws = make_wsel(l, -1.f);
  #pragma unroll
  for (int m = 0; m < 16; ++m) v[m] = __half22float2(A[l + 32*m]);

  if (mode == RM_CONV) {
    const __half2* G = g + (size_t)row * 512;
    float2 gv[16];
    #pragma unroll
    for (int m = 0; m < 16; ++m) gv[m] = __half22float2(G[l + 32*m]);
    fft512_fwd(v, l, -1.f, ws);
    #pragma unroll
    for (int r = 0; r < 16; ++r) v[r] = cmulf(v[r], gv[r]);
    fft512_inv(v, l, -1.f, ws);
    #pragma unroll
    for (int m = 0; m < 16; ++m) {
      int cidx = l + 32*m;
      float2 w = sc_turn(INVLT * (float)(cidx * row));   // conj four-step twiddle
      float2 r_ = cmulf(v[m], w);
      A[cidx] = __float22half2_rn(
          make_float2(r_.x * (1.f/(float)L1FFT), r_.y * (1.f/(float)L1FFT)));
    }
  } else {
    fft512_fwd(v, l, -1.f, ws);
    #pragma unroll
    for (int r = 0; r < 16; ++r) A[l + 32*r] = __float22half2_rn(v[r]);  // FFT-state order
  }
}

__global__ void diag_ws_too_small(float* out) { out[0] = 123456.0f; }

extern "C" void kernel_launch(void* const* d_in, const int* in_sizes, int n_in,
                              void* d_out, int out_size, void* d_ws, size_t ws_size,
                              hipStream_t stream) {
  const float* x = (const float*)d_in[0];   // (32,4,131072) f32
  const float* h = (const float*)d_in[1];   // (32,4,32768)  f32
  float* out = (float*)d_out;

  const size_t fixedB   = 2ull * L1FFT * sizeof(__half2);
  const size_t perChanB = (size_t)L1FFT * sizeof(__half2) + (size_t)MBINS * sizeof(__half2);
  if (ws_size < fixedB + perChanB) {
    diag_ws_too_small<<<1, 1, 0, stream>>>(out);
    return;
  }
  int chunk = (int)((ws_size - fixedB) / perChanB);
  if (chunk > NCHAN) chunk = NCHAN;

  __half2* V1 = (__half2*)d_ws;
  __half2* W  = V1 + L1FFT;
  __half2* A  = W + L1FFT;
  __half2* Hc = A + (size_t)chunk * L1FFT;

  dim3 blkC(512), blkR(256);
  dim3 gC1(32, 1), gR1(64, 1);

  // chirp-kernel spectra (channel-independent)
  pass_col_k<<<gC1, blkC, 0, stream>>>(CM_BUILD, nullptr, 0, nullptr, nullptr,
                                       V1, nullptr, nullptr, CN1, +1.f, -(XLEN-1), MBINS-1);
  pass_row_k<<<gR1, blkR, 0, stream>>>(RM_BUILD, V1, nullptr);
  pass_col_k<<<gC1, blkC, 0, stream>>>(CM_BUILD, nullptr, 0, nullptr, nullptr,
                                       W, nullptr, nullptr, CN2, -1.f, -(MBINS-1), XLEN-1);
  pass_row_k<<<gR1, blkR, 0, stream>>>(RM_BUILD, W, nullptr);

  for (int ch0 = 0; ch0 < NCHAN; ch0 += chunk) {
    int nc = NCHAN - ch0; if (nc > chunk) nc = chunk;
    dim3 gC(32, nc), gR(64, nc);
    const float* hq = h   + (size_t)ch0 * HLEN;
    const float* xq = x   + (size_t)ch0 * XLEN;
    float*       oq = out + (size_t)ch0 * XLEN;

    // H[k] -> Hc ([c][n] layout, half2, postchirp+rechirp+eps/CN2 applied)
    pass_col_k<<<gC, blkC, 0, stream>>>(CM_REAL, hq, HLEN, nullptr, nullptr,
                                        A, nullptr, nullptr, CN1, 0.f, 0, 0);
    pass_row_k<<<gR, blkR, 0, stream>>>(RM_CONV, A, V1);
    pass_col_k<<<gC, blkC, 0, stream>>>(CM_EXTRACT, nullptr, 0, A, nullptr,
                                        nullptr, Hc, nullptr, CN1, 0.f, 0, 0);

    // X path + combine + inverse-chirp transform
    pass_col_k<<<gC, blkC, 0, stream>>>(CM_REAL, xq, XLEN, nullptr, nullptr,
                                        A, nullptr, nullptr, CN1, 0.f, 0, 0);
    pass_row_k<<<gR, blkR, 0, stream>>>(RM_CONV, A, V1);
    pass_col_k<<<gC, blkC, 0, stream>>>(CM_COMBINE, nullptr, 0, A, Hc,
                                        A, nullptr, nullptr, CN2, 0.f, 0, 0);
    pass_row_k<<<gR, blkR, 0, stream>>>(RM_CONV, A, W);
    pass_col_k<<<gC, blkC, 0, stream>>>(CM_FINAL, nullptr, 0, A, nullptr,
                                        nullptr, nullptr, oq, CN2, 0.f, 0, 0);
  }
}

// Round 3
// 1131.391 us; speedup vs baseline: 1.1675x; 1.1675x over previous
//
#include <hip/hip_runtime.h>
#include <hip/hip_fp16.h>

// Literal replication of the reference:
//   X = rfft(x, n=163839); H = rfft(h, n=163839); y = irfft(X*H)[:131072]
// N1=163839, N2=163838 -> Bluestein on L=2^18; four-step 512x512.
// R5: fp16 stored intermediates, fp32 register math.
// R6: fetch-granularity fix (worked) but 512-thr blocks killed barrier overlap.
// R7: 256-thr / 8-col blocks restored + PAIR interleaved layout:
//     element (row,pos) of each 512x512 half2 intermediate lives at
//     (row>>1)*1024 + pos*2 + (row&1). Col-pass gathers/scatters then move
//     16 consecutive half2 (64 B) per 16-lane group; row pass stays fully
//     coalesced (wave = row pair, 1 dword/lane). Keeps WSel/h0/folded-Hc.

#define L1FFT 262144
#define NCHAN 128
#define CN1 163839LL
#define CN2 163838LL
#define MBINS 81920
#define XLEN 131072
#define HLEN 32768
#define TWO_PI 6.28318530717958647692f
#define INV512T (1.0f/512.0f)
#define INVLT   (1.0f/262144.0f)
#define CHIRP12 ((float)(0.5 / (163839.0 * 163838.0)))   // turns per k^2

#define CM_BUILD   0
#define CM_REAL    1
#define CM_COMBINE 2
#define CM_EXTRACT 3
#define CM_FINAL   4
#define RM_BUILD   0
#define RM_CONV    1

// half2 tile column stride (8 cols): 514 % 32 == 2 -> compute maps conflict-free
#define TS  514
// float stride for CM_FINAL alias (only 256 rows needed)
#define TFS 257

__device__ __forceinline__ float2 cmulf(float2 a, float2 b) {
  return make_float2(a.x*b.x - a.y*b.y, a.x*b.y + a.y*b.x);
}
__device__ __forceinline__ float2 cmulcf(float2 a, float2 b) {  // a * conj(b)
  return make_float2(a.x*b.x + a.y*b.y, a.y*b.x - a.x*b.y);
}
__device__ __forceinline__ float2 caddf(float2 a, float2 b){ return make_float2(a.x+b.x, a.y+b.y); }
__device__ __forceinline__ float2 csubf(float2 a, float2 b){ return make_float2(a.x-b.x, a.y-b.y); }

// e^{i*2pi*t} — native HW sin/cos take revolutions (v_sin_f32: sin(S0*2pi))
__device__ __forceinline__ float2 sc_turn(float t) {
  return make_float2(__builtin_amdgcn_cosf(t), __builtin_amdgcn_sinf(t));
}

// e^{sgn*i*pi*n^2/N1}: exact int64 mod by compile-time 2*N1, then turns
__device__ __forceinline__ float2 chirp1(float sgn, long long n) {
  long long m = (n*n) % (2*CN1);
  return sc_turn(sgn * (float)m * (1.0f/(float)(2*CN1)));
}
// e^{sgn*i*pi*n^2/N2}
__device__ __forceinline__ float2 chirp2(float sgn, long long n) {
  long long m = (n*n) % (2*CN2);
  return sc_turn(sgn * (float)m * (1.0f/(float)(2*CN2)));
}
// generic (runtime Q) — only used by the tiny BUILD dispatches
__device__ __forceinline__ float2 chirpv(float sgn, long long Q, long long n) {
  long long m = (n*n) % (2*Q);
  float ang = sgn * (0.5f*TWO_PI) * (float)m / (float)Q;
  float s, c; __sincosf(ang, &s, &c);
  return make_float2(c, s);
}

__device__ __forceinline__ int brev4(int x) {
  return ((x&1)<<3) | ((x&2)<<1) | ((x&4)>>1) | ((x&8)>>3);
}
__device__ __forceinline__ int brev5(int x) {
  return (int)(__brev((unsigned)x) >> 27);
}
__device__ __forceinline__ float2 shflx(float2 a, int m) {
  return make_float2(__shfl_xor(a.x, m, 64), __shfl_xor(a.y, m, 64));
}

#define C16_1 0.9238795325f
#define C16_2 0.7071067812f
#define C16_3 0.3826834324f
__device__ __forceinline__ float c16t(int j) {
  const float C[8] = {1.f, C16_1, C16_2, C16_3, 0.f, -C16_3, -C16_2, -C16_1};
  return C[j];
}
__device__ __forceinline__ float s16t(int j) {
  const float S[8] = {0.f, C16_3, C16_2, C16_1, 1.f, C16_1, C16_2, C16_3};
  return S[j];
}

// ---- in-lane 16-point DIF, stages 2..4 (shared) ----
__device__ __forceinline__ void lane16_fwd_rest(float2 v[16], float dsg) {
  #pragma unroll
  for (int h = 0; h < 2; ++h)
    #pragma unroll
    for (int j = 0; j < 4; ++j) {
      int i0 = h*8 + j;
      float wr = c16t(2*j), wi = dsg * s16t(2*j);
      float2 a = v[i0], b = v[i0+4];
      v[i0] = caddf(a, b);
      float2 tt = csubf(a, b);
      v[i0+4] = make_float2(tt.x*wr - tt.y*wi, tt.x*wi + tt.y*wr);
    }
  #pragma unroll
  for (int q = 0; q < 4; ++q)
    #pragma unroll
    for (int j = 0; j < 2; ++j) {
      int i0 = q*4 + j;
      float2 a = v[i0], b = v[i0+2];
      v[i0] = caddf(a, b);
      float2 tt = csubf(a, b);
      v[i0+2] = (j == 0) ? tt : make_float2(-dsg*tt.y, dsg*tt.x);
    }
  #pragma unroll
  for (int p = 0; p < 8; ++p) {
    float2 a = v[2*p], b = v[2*p+1];
    v[2*p] = caddf(a, b);
    v[2*p+1] = csubf(a, b);
  }
}
// dense input
__device__ __forceinline__ void lane16_fwd(float2 v[16], float dsg) {
  #pragma unroll
  for (int j = 0; j < 8; ++j) {
    float wr = c16t(j), wi = dsg * s16t(j);
    float2 a = v[j], b = v[j+8];
    v[j] = caddf(a, b);
    float2 tt = csubf(a, b);
    v[j+8] = make_float2(tt.x*wr - tt.y*wi, tt.x*wi + tt.y*wr);
  }
  lane16_fwd_rest(v, dsg);
}
// v[8..15] known zero on entry (not read): stage 1 degenerates to v[j+8]=v[j]*w
__device__ __forceinline__ void lane16_fwd_h0(float2 v[16], float dsg) {
  #pragma unroll
  for (int j = 0; j < 8; ++j) {
    float wr = c16t(j), wi = dsg * s16t(j);
    float2 a = v[j];
    v[j+8] = make_float2(a.x*wr - a.y*wi, a.x*wi + a.y*wr);
  }
  lane16_fwd_rest(v, dsg);
}

// ---- in-lane 16-point inverse-mirror ----
__device__ __forceinline__ void lane16_inv(float2 v[16], float dsg) {
  #pragma unroll
  for (int p = 0; p < 8; ++p) {
    float2 a = v[2*p], b = v[2*p+1];
    v[2*p] = caddf(a, b);
    v[2*p+1] = csubf(a, b);
  }
  #pragma unroll
  for (int q = 0; q < 4; ++q)
    #pragma unroll
    for (int j = 0; j < 2; ++j) {
      int i0 = q*4 + j;
      float2 a = v[i0], b = v[i0+2];
      float2 tb = (j == 0) ? b : make_float2(dsg*b.y, -dsg*b.x);
      v[i0] = caddf(a, tb);
      v[i0+2] = csubf(a, tb);
    }
  #pragma unroll
  for (int h = 0; h < 2; ++h)
    #pragma unroll
    for (int j = 0; j < 4; ++j) {
      int i0 = h*8 + j;
      float wr = c16t(2*j), wi = dsg * s16t(2*j);
      float2 a = v[i0], b = v[i0+4];
      float2 tb = make_float2(b.x*wr + b.y*wi, b.y*wr - b.x*wi);
      v[i0] = caddf(a, tb);
      v[i0+4] = csubf(a, tb);
    }
  #pragma unroll
  for (int j = 0; j < 8; ++j) {
    float wr = c16t(j), wi = dsg * s16t(j);
    float2 a = v[j], b = v[j+8];
    float2 tb = make_float2(b.x*wr + b.y*wi, b.y*wr - b.x*wi);
    v[j] = caddf(a, tb);
    v[j+8] = csubf(a, tb);
  }
}

// Per-lane cross-stage twiddles, hi-lane-selected once (low lanes get 1+0i so
// the stage body is a uniform cmul — no per-reg cndmask).
struct WSel { float2 a16, a8, a4, a2; };
__device__ __forceinline__ WSel make_wsel(int l, float dsg) {
  const float2 one = make_float2(1.f, 0.f);
  WSel w;
  w.a16 = (l & 16) ? sc_turn(dsg * (1.0f/32.0f) * (float)(l & 15)) : one;
  w.a8  = (l & 8)  ? sc_turn(dsg * (1.0f/16.0f) * (float)(l & 7))  : one;
  w.a4  = (l & 4)  ? sc_turn(dsg * (1.0f/8.0f)  * (float)(l & 3))  : one;
  w.a2  = ((l & 2) && (l & 1)) ? make_float2(0.f, dsg) : one;
  return w;
}

#define XF(mask, w) {                                                          \
    bool hi = (l & (mask)) != 0;                                               \
    _Pragma("unroll")                                                          \
    for (int r = 0; r < 16; ++r) {                                             \
      float2 o = shflx(v[r], (mask));                                          \
      float2 d = hi ? csubf(o, v[r]) : caddf(v[r], o);                         \
      v[r] = cmulf(d, (w));                                                    \
    } }
#define XFP(mask) {                                                            \
    bool hi = (l & (mask)) != 0;                                               \
    _Pragma("unroll")                                                          \
    for (int r = 0; r < 16; ++r) {                                             \
      float2 o = shflx(v[r], (mask));                                          \
      v[r] = hi ? csubf(o, v[r]) : caddf(v[r], o);                             \
    } }
#define XI(mask, w) {                                                          \
    bool hi = (l & (mask)) != 0;                                               \
    _Pragma("unroll")                                                          \
    for (int r = 0; r < 16; ++r) {                                             \
      float2 b = cmulcf(v[r], (w));                                            \
      float2 o = shflx(b, (mask));                                             \
      v[r] = hi ? csubf(o, b) : caddf(b, o);                                   \
    } }
#define XIP(mask) {                                                            \
    bool hi = (l & (mask)) != 0;                                               \
    _Pragma("unroll")                                                          \
    for (int r = 0; r < 16; ++r) {                                             \
      float2 b = v[r];                                                         \
      float2 o = shflx(b, (mask));                                             \
      v[r] = hi ? csubf(o, b) : caddf(b, o);                                   \
    } }

// Full 512-pt forward: input lane l reg m = x[l+32m];
// output lane l reg r = X[brev4(r) + 16*brev5(l)].
__device__ __forceinline__ void fft512_core_fwd(float2 v[16], int l, float dsg,
                                                const WSel& w) {
  #pragma unroll
  for (int r = 1; r < 16; ++r)                // W512^{l*brev4(r)} — exact turns
    v[r] = cmulf(v[r], sc_turn(dsg * INV512T * (float)(l * brev4(r))));
  XF(16, w.a16); XF(8, w.a8); XF(4, w.a4); XF(2, w.a2); XFP(1);
}
__device__ __forceinline__ void fft512_fwd(float2 v[16], int l, float dsg,
                                           const WSel& w) {
  lane16_fwd(v, dsg);
  fft512_core_fwd(v, l, dsg, w);
}
__device__ __forceinline__ void fft512_fwd_h0(float2 v[16], int l, float dsg,
                                              const WSel& w) {
  lane16_fwd_h0(v, dsg);
  fft512_core_fwd(v, l, dsg, w);
}

// Unnormalized inverse (x512) of fft512_fwd(dsg)
__device__ __forceinline__ void fft512_inv(float2 v[16], int l, float dsg,
                                           const WSel& w) {
  XIP(1); XI(2, w.a2); XI(4, w.a4); XI(8, w.a8); XI(16, w.a16);
  #pragma unroll
  for (int r = 1; r < 16; ++r)
    v[r] = cmulf(v[r], sc_turn(-dsg * INV512T * (float)(l * brev4(r))));
  lane16_inv(v, dsg);
}

// PAIR layout: half2 element (row,pos) of a 512x512 array at
//   (row>>1)*1024 + pos*2 + (row&1)

// ---------------- column pass (256 threads, 8 columns/block) ----------------
__global__ __launch_bounds__(256) void pass_col_k(
    int mode,
    const float* __restrict__ realSrc, int realLen,
    const __half2* cplxSrc,
    const __half2* __restrict__ hcIn,
    __half2* dstFull,
    __half2* __restrict__ specOut,
    float* __restrict__ realOut,
    long long Q, float csgn, int lo, int hi)
{
  // half2 tile: 8 cols * 514 = 16448 B; FINAL aliases float 8*257*4 = 8224 B
  __shared__ __align__(16) unsigned char ldsraw[8 * TS * 4];
  __half2* tile = (__half2*)ldsraw;
  const int t   = threadIdx.x;
  const int c0  = blockIdx.x * 8;
  const int ch  = blockIdx.y;
  const int l   = t & 31;
  const int ccf = t >> 5;
  const int c   = c0 + ccf;
  float2 v[16];
  WSel ws = make_wsel(l, -1.f);

  if (mode == CM_BUILD) {
    #pragma unroll
    for (int m = 0; m < 16; ++m) {
      int n = ((l + 32*m) << 9) + c;
      int np = (n <= hi) ? n : n - L1FFT;
      v[m] = (np >= lo) ? chirpv(csgn, Q, (long long)np) : make_float2(0.f, 0.f);
    }
  } else if (mode == CM_REAL) {
    // input rows >= 256 are zero (realLen <= 131072) — stage rows < 256 only
    #pragma unroll
    for (int i = 0; i < 8; ++i) {
      int qq = t + 256*i;
      int cc = qq & 7, r = qq >> 3;           // r < 256
      int n = (r << 9) + c0 + cc;
      float2 val = make_float2(0.f, 0.f);
      if (n < realLen) {
        float xv = realSrc[(size_t)ch * realLen + n];
        float2 cw = chirp1(-1.f, (long long)n);        // pre-chirp
        val = make_float2(xv*cw.x, xv*cw.y);
      }
      tile[cc*TS + r] = __float22half2_rn(val);
    }
    __syncthreads();
    #pragma unroll
    for (int m = 0; m < 8; ++m) v[m] = __half22float2(tile[ccf*TS + l + 32*m]);
    __syncthreads();
  } else {
    // PAIR gather: 16 consecutive half2 (2 rows x 8 cols) per 16-lane group
    #pragma unroll
    for (int i = 0; i < 16; ++i) {
      int qq = t + 256*i;
      int par = qq & 1, cc = (qq >> 1) & 7, rp = qq >> 4;
      int j = 2*rp + par;                              // physical row (FFT bin)
      int slot = brev5(j >> 4) + 32*brev4(j & 15);     // FFT-state slot
      tile[cc*TS + slot] =
          cplxSrc[(size_t)ch*L1FFT + (size_t)rp*1024 + (c0 + cc)*2 + par];
    }
    __syncthreads();
    #pragma unroll
    for (int m = 0; m < 16; ++m) v[m] = __half22float2(tile[ccf*TS + l + 32*m]);
    __syncthreads();
  }

  if (mode == CM_COMBINE) {
    fft512_inv(v, l, -1.f, ws);     // completes X's Bluestein conv
    #pragma unroll
    for (int m = 0; m <= 4; ++m) {  // n < 160 <=> k < MBINS
      int n = l + 32*m;
      // Hc already carries postchirp1*prechirp2*eps/CN2 (folded at EXTRACT)
      float2 H = __half22float2(hcIn[(size_t)ch*MBINS + c*160 + n]);
      v[m] = cmulf(v[m], H);
    }
    #pragma unroll
    for (int m = 5; m < 8; ++m) v[m] = make_float2(0.f, 0.f);
  }

  if (mode <= CM_COMBINE) {         // BUILD / REAL / COMBINE: fwd FFT + store
    if (mode == CM_BUILD) fft512_fwd(v, l, -1.f, ws);
    else                  fft512_fwd_h0(v, l, -1.f, ws);  // upper half zero
    #pragma unroll
    for (int r = 0; r < 16; ++r) {  // four-step twiddle (exact turns) + slot write
      int k1 = brev4(r), k2 = brev5(l);
      int kf = k1 + 16*k2;
      float2 w = sc_turn(-INVLT * (float)(c * kf));
      tile[ccf*TS + k2 + 32*k1] = __float22half2_rn(cmulf(v[r], w));
    }
    __syncthreads();
    {
      // PAIR scatter: natural-bin rows, 64 B per 16-lane group
      #pragma unroll
      for (int i = 0; i < 16; ++i) {
        int qq = t + 256*i;
        int par = qq & 1, cc = (qq >> 1) & 7, rp = qq >> 4;
        int row = 2*rp + par;                          // FFT bin (natural order)
        int slot = 32*(row & 15) + (row >> 4);         // tile slot holding it
        dstFull[(size_t)ch*L1FFT + (size_t)rp*1024 + (c0 + cc)*2 + par] =
            tile[cc*TS + slot];
      }
    }
  } else if (mode == CM_EXTRACT) {
    fft512_inv(v, l, -1.f, ws);
    #pragma unroll
    for (int m = 0; m <= 4; ++m) {
      int n = l + 32*m;
      long long k = ((long long)n << 9) + c;
      float2 cw = chirp1(-1.f, k);                 // postchirp of conv1
      float fk = (float)k;
      float2 wc = sc_turn(fk * fk * CHIRP12);      // rechirp for conv2 (N1-N2=1)
      float eps = (k == 0 || k == MBINS-1) ? 1.f : 2.f;
      float sc = eps / (float)CN2;
      float2 cw2 = cmulf(cw, wc);
      cw2 = make_float2(cw2.x*sc, cw2.y*sc);
      specOut[(size_t)ch*MBINS + c*160 + n] = __float22half2_rn(cmulf(v[m], cw2));
    }
  } else {                          // CM_FINAL
    fft512_inv(v, l, -1.f, ws);
    float* tf = (float*)ldsraw;
    #pragma unroll
    for (int m = 0; m < 8; ++m) {
      int n = l + 32*m;
      long long nb = ((long long)n << 9) + c;
      float2 cw = chirp2(+1.f, nb);
      tf[ccf*TFS + n] = v[m].x*cw.x - v[m].y*cw.y;
    }
    __syncthreads();
    {
      int cc = t & 7, u = t >> 3;
      #pragma unroll
      for (int i = 0; i < 8; ++i) {
        int n = u + 32*i;
        realOut[(size_t)ch*XLEN + (n << 9) + c0 + cc] = tf[cc*TFS + n];
      }
    }
  }
}

// ---------------- row pass (LDS-free, 256 threads, PAIR layout) --------------
__global__ __launch_bounds__(256) void pass_row_k(
    int mode, __half2* a, const __half2* __restrict__ g)
{
  const int t = threadIdx.x;
  const int l = t & 31;
  const int w8 = t >> 5;                      // 0..7
  const int row = blockIdx.x * 8 + w8;
  const int rp  = row >> 1, par = row & 1;    // wave = row pair (w8 = 2q, 2q+1)
  const int ch = blockIdx.y;
  // PAIR: (row, pos) -> rp*1024 + pos*2 + par; pos = l + 32m -> +64m
  __half2* A = a + (size_t)ch * L1FFT + (size_t)rp * 1024 + 2*l + par;
  float2 v[16];
  WSel ws = make_wsel(l, -1.f);
  #pragma unroll
  for (int m = 0; m < 16; ++m) v[m] = __half22float2(A[64*m]);

  if (mode == RM_CONV) {
    const __half2* G = g + (size_t)rp * 1024 + 2*l + par;
    float2 gv[16];
    #pragma unroll
    for (int m = 0; m < 16; ++m) gv[m] = __half22float2(G[64*m]);
    fft512_fwd(v, l, -1.f, ws);
    #pragma unroll
    for (int r = 0; r < 16; ++r) v[r] = cmulf(v[r], gv[r]);
    fft512_inv(v, l, -1.f, ws);
    #pragma unroll
    for (int m = 0; m < 16; ++m) {
      int cidx = l + 32*m;
      float2 w = sc_turn(INVLT * (float)(cidx * row));   // conj four-step twiddle
      float2 r_ = cmulf(v[m], w);
      A[64*m] = __float22half2_rn(
          make_float2(r_.x * (1.f/(float)L1FFT), r_.y * (1.f/(float)L1FFT)));
    }
  } else {
    fft512_fwd(v, l, -1.f, ws);
    #pragma unroll
    for (int r = 0; r < 16; ++r) A[64*r] = __float22half2_rn(v[r]);  // state order
  }
}

__global__ void diag_ws_too_small(float* out) { out[0] = 123456.0f; }

extern "C" void kernel_launch(void* const* d_in, const int* in_sizes, int n_in,
                              void* d_out, int out_size, void* d_ws, size_t ws_size,
                              hipStream_t stream) {
  const float* x = (const float*)d_in[0];   // (32,4,131072) f32
  const float* h = (const float*)d_in[1];   // (32,4,32768)  f32
  float* out = (float*)d_out;

  const size_t fixedB   = 2ull * L1FFT * sizeof(__half2);
  const size_t perChanB = (size_t)L1FFT * sizeof(__half2) + (size_t)MBINS * sizeof(__half2);
  if (ws_size < fixedB + perChanB) {
    diag_ws_too_small<<<1, 1, 0, stream>>>(out);
    return;
  }
  int chunk = (int)((ws_size - fixedB) / perChanB);
  if (chunk > NCHAN) chunk = NCHAN;

  __half2* V1 = (__half2*)d_ws;
  __half2* W  = V1 + L1FFT;
  __half2* A  = W + L1FFT;
  __half2* Hc = A + (size_t)chunk * L1FFT;

  dim3 blk(256);
  dim3 g1(64, 1);

  // chirp-kernel spectra (channel-independent)
  pass_col_k<<<g1, blk, 0, stream>>>(CM_BUILD, nullptr, 0, nullptr, nullptr,
                                     V1, nullptr, nullptr, CN1, +1.f, -(XLEN-1), MBINS-1);
  pass_row_k<<<g1, blk, 0, stream>>>(RM_BUILD, V1, nullptr);
  pass_col_k<<<g1, blk, 0, stream>>>(CM_BUILD, nullptr, 0, nullptr, nullptr,
                                     W, nullptr, nullptr, CN2, -1.f, -(MBINS-1), XLEN-1);
  pass_row_k<<<g1, blk, 0, stream>>>(RM_BUILD, W, nullptr);

  for (int ch0 = 0; ch0 < NCHAN; ch0 += chunk) {
    int nc = NCHAN - ch0; if (nc > chunk) nc = chunk;
    dim3 gC(64, nc), gR(64, nc);
    const float* hq = h   + (size_t)ch0 * HLEN;
    const float* xq = x   + (size_t)ch0 * XLEN;
    float*       oq = out + (size_t)ch0 * XLEN;

    // H[k] -> Hc ([c][n] layout, half2, postchirp+rechirp+eps/CN2 applied)
    pass_col_k<<<gC, blk, 0, stream>>>(CM_REAL, hq, HLEN, nullptr, nullptr,
                                       A, nullptr, nullptr, CN1, 0.f, 0, 0);
    pass_row_k<<<gR, blk, 0, stream>>>(RM_CONV, A, V1);
    pass_col_k<<<gC, blk, 0, stream>>>(CM_EXTRACT, nullptr, 0, A, nullptr,
                                       nullptr, Hc, nullptr, CN1, 0.f, 0, 0);

    // X path + combine + inverse-chirp transform
    pass_col_k<<<gC, blk, 0, stream>>>(CM_REAL, xq, XLEN, nullptr, nullptr,
                                       A, nullptr, nullptr, CN1, 0.f, 0, 0);
    pass_row_k<<<gR, blk, 0, stream>>>(RM_CONV, A, V1);
    pass_col_k<<<gC, blk, 0, stream>>>(CM_COMBINE, nullptr, 0, A, Hc,
                                       A, nullptr, nullptr, CN2, 0.f, 0, 0);
    pass_row_k<<<gR, blk, 0, stream>>>(RM_CONV, A, W);
    pass_col_k<<<gC, blk, 0, stream>>>(CM_FINAL, nullptr, 0, A, nullptr,
                                       nullptr, nullptr, oq, CN2, 0.f, 0, 0);
  }
}

// Round 4
// 999.936 us; speedup vs baseline: 1.3210x; 1.1315x over previous
//
#include <hip/hip_runtime.h>
#include <hip/hip_fp16.h>

// Literal replication of the reference:
//   X = rfft(x, n=163839); H = rfft(h, n=163839); y = irfft(X*H)[:131072]
// N1=163839, N2=163838 -> Bluestein on L=2^18; four-step 512x512.
// R5: fp16 stored intermediates, fp32 register math.
// R7: PAIR interleaved layout, 256-thr blocks (64B segments + overlap).
// R8: (a) permuted row storage: bin kf lives at row-slot 32*brev4(kf&15)+
//     brev5(kf>>4) == (reg r, lane l) -> slot 32r+l. All LDS/global
//     gathers/scatters become LINEAR (bank conflicts ~0, index math gone);
//     row pass recomputes logical bin j from its slot for the one twiddle.
//     (b) packed-f32 complex math (ext_vector float2, fma-contractable,
//     s=+-1 butterflies) -> v_pk_* codegen, ~40% fewer VALU insts.

#define L1FFT 262144
#define NCHAN 128
#define CN1 163839LL
#define CN2 163838LL
#define MBINS 81920
#define XLEN 131072
#define HLEN 32768
#define TWO_PI 6.28318530717958647692f
#define INV512T (1.0f/512.0f)
#define INVLT   (1.0f/262144.0f)
#define CHIRP12 ((float)(0.5 / (163839.0 * 163838.0)))   // turns per k^2

#define CM_BUILD   0
#define CM_REAL    1
#define CM_COMBINE 2
#define CM_EXTRACT 3
#define CM_FINAL   4
#define RM_BUILD   0
#define RM_CONV    1

// half2 tile column stride: 518 (even -> uint2-aligned pairs; 518%32=6 ->
// all maps <=2-3-way). FINAL float alias stride 261 (5 mod 32).
#define TS  518
#define TFS 261

typedef float cplx __attribute__((ext_vector_type(2)));

__device__ __forceinline__ cplx mkc(float x, float y){ cplx r; r.x = x; r.y = y; return r; }
__device__ __forceinline__ cplx cmulf(cplx a, cplx b) {
  return a.xx*b + a.yy*mkc(-b.y, b.x);         // (ax bx - ay by, ax by + ay bx)
}
__device__ __forceinline__ cplx cmulcf(cplx a, cplx b) {  // a * conj(b)
  return a.yy*b.yx + a.xx*mkc(b.x, -b.y);      // (ax bx + ay by, ay bx - ax by)
}
// dsg * (-t.y, t.x)  == dsg * i * t
__device__ __forceinline__ cplx crot(cplx t, float dsg) {
  return mkc(-dsg*t.y, dsg*t.x);
}

// e^{i*2pi*t} — native HW sin/cos take revolutions (v_sin_f32: sin(S0*2pi))
__device__ __forceinline__ cplx sc_turn(float t) {
  return mkc(__builtin_amdgcn_cosf(t), __builtin_amdgcn_sinf(t));
}

// e^{sgn*i*pi*n^2/N1}: exact int64 mod by compile-time 2*N1, then turns
__device__ __forceinline__ cplx chirp1(float sgn, long long n) {
  long long m = (n*n) % (2*CN1);
  return sc_turn(sgn * (float)m * (1.0f/(float)(2*CN1)));
}
// e^{sgn*i*pi*n^2/N2}
__device__ __forceinline__ cplx chirp2(float sgn, long long n) {
  long long m = (n*n) % (2*CN2);
  return sc_turn(sgn * (float)m * (1.0f/(float)(2*CN2)));
}
// generic (runtime Q) — only used by the tiny BUILD dispatches
__device__ __forceinline__ cplx chirpv(float sgn, long long Q, long long n) {
  long long m = (n*n) % (2*Q);
  float ang = sgn * (0.5f*TWO_PI) * (float)m / (float)Q;
  float s, c; __sincosf(ang, &s, &c);
  return mkc(c, s);
}

__device__ __forceinline__ int brev4(int x) {
  return ((x&1)<<3) | ((x&2)<<1) | ((x&4)>>1) | ((x&8)>>3);
}
__device__ __forceinline__ int brev5(int x) {
  return (int)(__brev((unsigned)x) >> 27);
}
__device__ __forceinline__ cplx shflx(cplx a, int m) {
  return mkc(__shfl_xor(a.x, m, 64), __shfl_xor(a.y, m, 64));
}

__device__ __forceinline__ cplx h2c(__half2 h) {
  float2 f = __half22float2(h); return mkc(f.x, f.y);
}
__device__ __forceinline__ __half2 c2h(cplx c) {
  return __float22half2_rn(make_float2(c.x, c.y));
}

#define C16_1 0.9238795325f
#define C16_2 0.7071067812f
#define C16_3 0.3826834324f
__device__ __forceinline__ float c16t(int j) {
  const float C[8] = {1.f, C16_1, C16_2, C16_3, 0.f, -C16_3, -C16_2, -C16_1};
  return C[j];
}
__device__ __forceinline__ float s16t(int j) {
  const float S[8] = {0.f, C16_3, C16_2, C16_1, 1.f, C16_1, C16_2, C16_3};
  return S[j];
}

// ---- in-lane 16-point DIF, stages 2..4 (shared) ----
__device__ __forceinline__ void lane16_fwd_rest(cplx v[16], float dsg) {
  #pragma unroll
  for (int h = 0; h < 2; ++h)
    #pragma unroll
    for (int j = 0; j < 4; ++j) {
      int i0 = h*8 + j;
      cplx w = mkc(c16t(2*j), dsg * s16t(2*j));
      cplx a = v[i0], b = v[i0+4];
      v[i0] = a + b;
      v[i0+4] = cmulf(a - b, w);
    }
  #pragma unroll
  for (int q = 0; q < 4; ++q)
    #pragma unroll
    for (int j = 0; j < 2; ++j) {
      int i0 = q*4 + j;
      cplx a = v[i0], b = v[i0+2];
      cplx tt = a - b;
      v[i0] = a + b;
      v[i0+2] = (j == 0) ? tt : crot(tt, dsg);
    }
  #pragma unroll
  for (int p = 0; p < 8; ++p) {
    cplx a = v[2*p], b = v[2*p+1];
    v[2*p] = a + b;
    v[2*p+1] = a - b;
  }
}
// dense input
__device__ __forceinline__ void lane16_fwd(cplx v[16], float dsg) {
  #pragma unroll
  for (int j = 0; j < 8; ++j) {
    cplx w = mkc(c16t(j), dsg * s16t(j));
    cplx a = v[j], b = v[j+8];
    v[j] = a + b;
    v[j+8] = cmulf(a - b, w);
  }
  lane16_fwd_rest(v, dsg);
}
// v[8..15] known zero on entry (not read): stage 1 degenerates to v[j+8]=v[j]*w
__device__ __forceinline__ void lane16_fwd_h0(cplx v[16], float dsg) {
  #pragma unroll
  for (int j = 0; j < 8; ++j) {
    cplx w = mkc(c16t(j), dsg * s16t(j));
    v[j+8] = cmulf(v[j], w);
  }
  lane16_fwd_rest(v, dsg);
}

// ---- in-lane 16-point inverse-mirror ----
__device__ __forceinline__ void lane16_inv(cplx v[16], float dsg) {
  #pragma unroll
  for (int p = 0; p < 8; ++p) {
    cplx a = v[2*p], b = v[2*p+1];
    v[2*p] = a + b;
    v[2*p+1] = a - b;
  }
  #pragma unroll
  for (int q = 0; q < 4; ++q)
    #pragma unroll
    for (int j = 0; j < 2; ++j) {
      int i0 = q*4 + j;
      cplx a = v[i0], b = v[i0+2];
      cplx tb = (j == 0) ? b : crot(b, -dsg);
      v[i0] = a + tb;
      v[i0+2] = a - tb;
    }
  #pragma unroll
  for (int h = 0; h < 2; ++h)
    #pragma unroll
    for (int j = 0; j < 4; ++j) {
      int i0 = h*8 + j;
      cplx w = mkc(c16t(2*j), dsg * s16t(2*j));
      cplx a = v[i0], b = v[i0+4];
      cplx tb = cmulcf(b, w);
      v[i0] = a + tb;
      v[i0+4] = a - tb;
    }
  #pragma unroll
  for (int j = 0; j < 8; ++j) {
    cplx w = mkc(c16t(j), dsg * s16t(j));
    cplx a = v[j], b = v[j+8];
    cplx tb = cmulcf(b, w);
    v[j] = a + tb;
    v[j+8] = a - tb;
  }
}

// Per-lane cross-stage twiddles, hi-lane-selected once (low lanes get 1+0i so
// the stage body is a uniform cmul — no per-reg cndmask).
struct WSel { cplx a16, a8, a4, a2; };
__device__ __forceinline__ WSel make_wsel(int l, float dsg) {
  const cplx one = mkc(1.f, 0.f);
  WSel w;
  w.a16 = (l & 16) ? sc_turn(dsg * (1.0f/32.0f) * (float)(l & 15)) : one;
  w.a8  = (l & 8)  ? sc_turn(dsg * (1.0f/16.0f) * (float)(l & 7))  : one;
  w.a4  = (l & 4)  ? sc_turn(dsg * (1.0f/8.0f)  * (float)(l & 3))  : one;
  w.a2  = ((l & 2) && (l & 1)) ? mkc(0.f, dsg) : one;
  return w;
}

// butterfly as o + s*v (s = +-1 per stage, hoisted): one v_pk_fma each
#define XF(mask, w) {                                                          \
    const float s_ = ((l & (mask)) != 0) ? -1.f : 1.f;                         \
    _Pragma("unroll")                                                          \
    for (int r = 0; r < 16; ++r) {                                             \
      cplx o = shflx(v[r], (mask));                                            \
      v[r] = cmulf(o + s_*v[r], (w));                                          \
    } }
#define XFP(mask) {                                                            \
    const float s_ = ((l & (mask)) != 0) ? -1.f : 1.f;                         \
    _Pragma("unroll")                                                          \
    for (int r = 0; r < 16; ++r) {                                             \
      cplx o = shflx(v[r], (mask));                                            \
      v[r] = o + s_*v[r];                                                      \
    } }
#define XI(mask, w) {                                                          \
    const float s_ = ((l & (mask)) != 0) ? -1.f : 1.f;                         \
    _Pragma("unroll")                                                          \
    for (int r = 0; r < 16; ++r) {                                             \
      cplx b = cmulcf(v[r], (w));                                              \
      cplx o = shflx(b, (mask));                                               \
      v[r] = o + s_*b;                                                         \
    } }
#define XIP(mask) {                                                            \
    const float s_ = ((l & (mask)) != 0) ? -1.f : 1.f;                         \
    _Pragma("unroll")                                                          \
    for (int r = 0; r < 16; ++r) {                                             \
      cplx b = v[r];                                                           \
      cplx o = shflx(b, (mask));                                               \
      v[r] = o + s_*b;                                                         \
    } }

// Full 512-pt forward: input lane l reg m = x[l+32m];
// output lane l reg r = X[brev4(r) + 16*brev5(l)].
__device__ __forceinline__ void fft512_core_fwd(cplx v[16], int l, float dsg,
                                                const WSel& w) {
  #pragma unroll
  for (int r = 1; r < 16; ++r)                // W512^{l*brev4(r)} — exact turns
    v[r] = cmulf(v[r], sc_turn(dsg * INV512T * (float)(l * brev4(r))));
  XF(16, w.a16); XF(8, w.a8); XF(4, w.a4); XF(2, w.a2); XFP(1);
}
__device__ __forceinline__ void fft512_fwd(cplx v[16], int l, float dsg,
                                           const WSel& w) {
  lane16_fwd(v, dsg);
  fft512_core_fwd(v, l, dsg, w);
}
__device__ __forceinline__ void fft512_fwd_h0(cplx v[16], int l, float dsg,
                                              const WSel& w) {
  lane16_fwd_h0(v, dsg);
  fft512_core_fwd(v, l, dsg, w);
}

// Unnormalized inverse (x512) of fft512_fwd(dsg)
__device__ __forceinline__ void fft512_inv(cplx v[16], int l, float dsg,
                                           const WSel& w) {
  XIP(1); XI(2, w.a2); XI(4, w.a4); XI(8, w.a8); XI(16, w.a16);
  #pragma unroll
  for (int r = 1; r < 16; ++r)
    v[r] = cmulf(v[r], sc_turn(-dsg * INV512T * (float)(l * brev4(r))));
  lane16_inv(v, dsg);
}

// Storage layout of 512x512 half2 intermediates:
//   row dimension: PERMUTED — bin kf lives at row-slot rs = p(kf) where
//   p(kf) = 32*brev4(kf&15) + brev5(kf>>4); for the col-FFT register (l,r)
//   holding bin brev4(r)+16*brev5(l), rs = 32*r + l (LINEAR in reg/lane).
//   pos dimension: PAIR interleave — (rs, pos) at (rs>>1)*1024 + pos*2 + (rs&1).
//   Logical bin from slot: j(rs) = 16*brev5(rs&31) + brev4(rs>>5).

// ---------------- column pass (256 threads, 8 columns/block) ----------------
__global__ __launch_bounds__(256) void pass_col_k(
    int mode,
    const float* __restrict__ realSrc, int realLen,
    const __half2* cplxSrc,
    const __half2* __restrict__ hcIn,
    __half2* dstFull,
    __half2* __restrict__ specOut,
    float* __restrict__ realOut,
    long long Q, float csgn, int lo, int hi)
{
  // half2 tile: 8 cols * 518 = 16576 B; FINAL aliases float 8*261*4 = 8352 B
  __shared__ __align__(16) unsigned char ldsraw[8 * TS * 4];
  __half2* tile = (__half2*)ldsraw;
  const int t   = threadIdx.x;
  const int c0  = blockIdx.x * 8;
  const int ch  = blockIdx.y;
  const int l   = t & 31;
  const int ccf = t >> 5;
  const int c   = c0 + ccf;
  cplx v[16];
  WSel ws = make_wsel(l, -1.f);

  if (mode == CM_BUILD) {
    #pragma unroll
    for (int m = 0; m < 16; ++m) {
      int n = ((l + 32*m) << 9) + c;
      int np = (n <= hi) ? n : n - L1FFT;
      v[m] = (np >= lo) ? chirpv(csgn, Q, (long long)np) : mkc(0.f, 0.f);
    }
  } else if (mode == CM_REAL) {
    // input rows >= 256 are zero (realLen <= 131072) — stage rows < 256 only
    #pragma unroll
    for (int i = 0; i < 8; ++i) {
      int qq = t + 256*i;
      int cc = qq & 7, r = qq >> 3;           // r < 256
      int n = (r << 9) + c0 + cc;
      cplx val = mkc(0.f, 0.f);
      if (n < realLen) {
        float xv = realSrc[(size_t)ch * realLen + n];
        val = chirp1(-1.f, (long long)n) * xv;        // pre-chirp
      }
      tile[cc*TS + r] = c2h(val);
    }
    __syncthreads();
    #pragma unroll
    for (int m = 0; m < 8; ++m) v[m] = h2c(tile[ccf*TS + l + 32*m]);
    __syncthreads();
  } else {
    // LINEAR gather (permuted rows): uint2 = 2 half2 = 2 row-slots per thread
    const uint2* srcp = (const uint2*)(cplxSrc + (size_t)ch * L1FFT);
    #pragma unroll
    for (int i = 0; i < 8; ++i) {
      int qq = t + 256*i;
      int cc = qq & 7, rp = qq >> 3;          // rp < 256 (row-slot pair)
      uint2 val = srcp[(size_t)rp*512 + c0 + cc];
      *(uint2*)&tile[cc*TS + 2*rp] = val;
    }
    __syncthreads();
    #pragma unroll
    for (int m = 0; m < 16; ++m) v[m] = h2c(tile[ccf*TS + l + 32*m]);
    __syncthreads();
  }

  if (mode == CM_COMBINE) {
    fft512_inv(v, l, -1.f, ws);     // completes X's Bluestein conv
    #pragma unroll
    for (int m = 0; m <= 4; ++m) {  // n < 160 <=> k < MBINS
      int n = l + 32*m;
      // Hc already carries postchirp1*prechirp2*eps/CN2 (folded at EXTRACT)
      cplx H = h2c(hcIn[(size_t)ch*MBINS + c*160 + n]);
      v[m] = cmulf(v[m], H);
    }
    #pragma unroll
    for (int m = 5; m < 8; ++m) v[m] = mkc(0.f, 0.f);
  }

  if (mode <= CM_COMBINE) {         // BUILD / REAL / COMBINE: fwd FFT + store
    if (mode == CM_BUILD) fft512_fwd(v, l, -1.f, ws);
    else                  fft512_fwd_h0(v, l, -1.f, ws);  // upper half zero
    #pragma unroll
    for (int r = 0; r < 16; ++r) {  // four-step twiddle + LINEAR slot write
      int kf = brev4(r) + 16*brev5(l);
      cplx w = sc_turn(-INVLT * (float)(c * kf));
      tile[ccf*TS + l + 32*r] = c2h(cmulf(v[r], w));     // rs = 32r + l
    }
    __syncthreads();
    {
      uint2* dstp = (uint2*)(dstFull + (size_t)ch * L1FFT);
      #pragma unroll
      for (int i = 0; i < 8; ++i) {
        int qq = t + 256*i;
        int cc = qq & 7, rp = qq >> 3;
        dstp[(size_t)rp*512 + c0 + cc] = *(const uint2*)&tile[cc*TS + 2*rp];
      }
    }
  } else if (mode == CM_EXTRACT) {
    fft512_inv(v, l, -1.f, ws);
    #pragma unroll
    for (int m = 0; m <= 4; ++m) {
      int n = l + 32*m;
      long long k = ((long long)n << 9) + c;
      cplx cw = chirp1(-1.f, k);                 // postchirp of conv1
      float fk = (float)k;
      cplx wc = sc_turn(fk * fk * CHIRP12);      // rechirp for conv2 (N1-N2=1)
      float eps = (k == 0 || k == MBINS-1) ? 1.f : 2.f;
      float sc = eps / (float)CN2;
      cplx cw2 = cmulf(cw, wc) * sc;
      specOut[(size_t)ch*MBINS + c*160 + n] = c2h(cmulf(v[m], cw2));
    }
  } else {                          // CM_FINAL
    fft512_inv(v, l, -1.f, ws);
    float* tf = (float*)ldsraw;
    #pragma unroll
    for (int m = 0; m < 8; ++m) {
      int n = l + 32*m;
      long long nb = ((long long)n << 9) + c;
      cplx cw = chirp2(+1.f, nb);
      tf[ccf*TFS + n] = v[m].x*cw.x - v[m].y*cw.y;
    }
    __syncthreads();
    {
      int cc = t & 7, u = t >> 3;
      #pragma unroll
      for (int i = 0; i < 8; ++i) {
        int n = u + 32*i;
        realOut[(size_t)ch*XLEN + (n << 9) + c0 + cc] = tf[cc*TFS + n];
      }
    }
  }
}

// ---------------- row pass (LDS-free, 256 threads, PAIR layout) --------------
__global__ __launch_bounds__(256) void pass_row_k(
    int mode, __half2* a, const __half2* __restrict__ g)
{
  const int t = threadIdx.x;
  const int l = t & 31;
  const int w8 = t >> 5;                      // 0..7
  const int rs = blockIdx.x * 8 + w8;         // storage row-slot
  const int rp = rs >> 1, par = rs & 1;       // wave = slot pair
  const int ch = blockIdx.y;
  // logical FFT bin of this storage slot (for the four-step twiddle)
  const int j = 16*brev5(rs & 31) + brev4(rs >> 5);
  // PAIR: (rs, pos) -> rp*1024 + pos*2 + par; pos = l + 32m -> +64m
  __half2* A = a + (size_t)ch * L1FFT + (size_t)rp * 1024 + 2*l + par;
  cplx v[16];
  WSel ws = make_wsel(l, -1.f);
  #pragma unroll
  for (int m = 0; m < 16; ++m) v[m] = h2c(A[64*m]);

  if (mode == RM_CONV) {
    const __half2* G = g + (size_t)rp * 1024 + 2*l + par;
    cplx gv[16];
    #pragma unroll
    for (int m = 0; m < 16; ++m) gv[m] = h2c(G[64*m]);
    fft512_fwd(v, l, -1.f, ws);
    #pragma unroll
    for (int r = 0; r < 16; ++r) v[r] = cmulf(v[r], gv[r]);
    fft512_inv(v, l, -1.f, ws);
    #pragma unroll
    for (int m = 0; m < 16; ++m) {
      int cidx = l + 32*m;
      cplx w = sc_turn(INVLT * (float)(cidx * j));   // conj four-step twiddle
      A[64*m] = c2h(cmulf(v[m], w) * (1.f/(float)L1FFT));
    }
  } else {
    fft512_fwd(v, l, -1.f, ws);
    #pragma unroll
    for (int r = 0; r < 16; ++r) A[64*r] = c2h(v[r]);  // state order
  }
}

__global__ void diag_ws_too_small(float* out) { out[0] = 123456.0f; }

extern "C" void kernel_launch(void* const* d_in, const int* in_sizes, int n_in,
                              void* d_out, int out_size, void* d_ws, size_t ws_size,
                              hipStream_t stream) {
  const float* x = (const float*)d_in[0];   // (32,4,131072) f32
  const float* h = (const float*)d_in[1];   // (32,4,32768)  f32
  float* out = (float*)d_out;

  const size_t fixedB   = 2ull * L1FFT * sizeof(__half2);
  const size_t perChanB = (size_t)L1FFT * sizeof(__half2) + (size_t)MBINS * sizeof(__half2);
  if (ws_size < fixedB + perChanB) {
    diag_ws_too_small<<<1, 1, 0, stream>>>(out);
    return;
  }
  int chunk = (int)((ws_size - fixedB) / perChanB);
  if (chunk > NCHAN) chunk = NCHAN;

  __half2* V1 = (__half2*)d_ws;
  __half2* W  = V1 + L1FFT;
  __half2* A  = W + L1FFT;
  __half2* Hc = A + (size_t)chunk * L1FFT;

  dim3 blk(256);
  dim3 g1(64, 1);

  // chirp-kernel spectra (channel-independent)
  pass_col_k<<<g1, blk, 0, stream>>>(CM_BUILD, nullptr, 0, nullptr, nullptr,
                                     V1, nullptr, nullptr, CN1, +1.f, -(XLEN-1), MBINS-1);
  pass_row_k<<<g1, blk, 0, stream>>>(RM_BUILD, V1, nullptr);
  pass_col_k<<<g1, blk, 0, stream>>>(CM_BUILD, nullptr, 0, nullptr, nullptr,
                                     W, nullptr, nullptr, CN2, -1.f, -(MBINS-1), XLEN-1);
  pass_row_k<<<g1, blk, 0, stream>>>(RM_BUILD, W, nullptr);

  for (int ch0 = 0; ch0 < NCHAN; ch0 += chunk) {
    int nc = NCHAN - ch0; if (nc > chunk) nc = chunk;
    dim3 gC(64, nc), gR(64, nc);
    const float* hq = h   + (size_t)ch0 * HLEN;
    const float* xq = x   + (size_t)ch0 * XLEN;
    float*       oq = out + (size_t)ch0 * XLEN;

    // H[k] -> Hc ([c][n] layout, half2, postchirp+rechirp+eps/CN2 applied)
    pass_col_k<<<gC, blk, 0, stream>>>(CM_REAL, hq, HLEN, nullptr, nullptr,
                                       A, nullptr, nullptr, CN1, 0.f, 0, 0);
    pass_row_k<<<gR, blk, 0, stream>>>(RM_CONV, A, V1);
    pass_col_k<<<gC, blk, 0, stream>>>(CM_EXTRACT, nullptr, 0, A, nullptr,
                                       nullptr, Hc, nullptr, CN1, 0.f, 0, 0);

    // X path + combine + inverse-chirp transform
    pass_col_k<<<gC, blk, 0, stream>>>(CM_REAL, xq, XLEN, nullptr, nullptr,
                                       A, nullptr, nullptr, CN1, 0.f, 0, 0);
    pass_row_k<<<gR, blk, 0, stream>>>(RM_CONV, A, V1);
    pass_col_k<<<gC, blk, 0, stream>>>(CM_COMBINE, nullptr, 0, A, Hc,
                                       A, nullptr, nullptr, CN2, 0.f, 0, 0);
    pass_row_k<<<gR, blk, 0, stream>>>(RM_CONV, A, W);
    pass_col_k<<<gC, blk, 0, stream>>>(CM_FINAL, nullptr, 0, A, nullptr,
                                       nullptr, nullptr, oq, CN2, 0.f, 0, 0);
  }
}

// Round 5
// 747.461 us; speedup vs baseline: 1.7672x; 1.3378x over previous
//
#include <hip/hip_runtime.h>
#include <hip/hip_fp16.h>

// Literal replication of the reference:
//   X = rfft(x, n=163839); H = rfft(h, n=163839); y = irfft(X*H)[:131072]
// N1=163839, N2=163838 -> Bluestein on L=2^18; four-step 512x512.
// R5: fp16 stored intermediates, fp32 register math.
// R7: PAIR interleaved layout, 256-thr blocks (64B segments + overlap).
// R8: permuted row storage (linear gathers) + packed-f32 complex math.
// R9: (a) shuffle stages for xor masks 1,2,8 moved to DPP (quad_perm /
//     row_ror:8, VALU pipe); masks 4,16 use imm ds_swizzle. DS-pipe ops per
//     FFT drop 160 -> 64 (theory: DS pipe was the uncounted bottleneck).
//     (b) twiddle transcendentals replaced by complex power chains:
//     FFT cores 15 sc_turn -> 1 (+14 cmul, binary chain, brev4 involution);
//     four-step twiddle 16 -> 2 (B,C factorization); row conj twiddle
//     16 -> 2 (geometric recurrence, 1/L folded in).

#define L1FFT 262144
#define NCHAN 128
#define CN1 163839LL
#define CN2 163838LL
#define MBINS 81920
#define XLEN 131072
#define HLEN 32768
#define TWO_PI 6.28318530717958647692f
#define INV512T (1.0f/512.0f)
#define INVLT   (1.0f/262144.0f)
#define CHIRP12 ((float)(0.5 / (163839.0 * 163838.0)))   // turns per k^2

#define CM_BUILD   0
#define CM_REAL    1
#define CM_COMBINE 2
#define CM_EXTRACT 3
#define CM_FINAL   4
#define RM_BUILD   0
#define RM_CONV    1

// half2 tile column stride: 518 (even -> uint2-aligned pairs; 518%32=6 ->
// all maps <=2-3-way). FINAL float alias stride 261 (5 mod 32).
#define TS  518
#define TFS 261

typedef float cplx __attribute__((ext_vector_type(2)));

__device__ __forceinline__ cplx mkc(float x, float y){ cplx r; r.x = x; r.y = y; return r; }
__device__ __forceinline__ cplx cmulf(cplx a, cplx b) {
  return a.xx*b + a.yy*mkc(-b.y, b.x);         // (ax bx - ay by, ax by + ay bx)
}
__device__ __forceinline__ cplx cmulcf(cplx a, cplx b) {  // a * conj(b)
  return a.yy*b.yx + a.xx*mkc(b.x, -b.y);      // (ax bx + ay by, ay bx - ax by)
}
// dsg * (-t.y, t.x)  == dsg * i * t
__device__ __forceinline__ cplx crot(cplx t, float dsg) {
  return mkc(-dsg*t.y, dsg*t.x);
}

// e^{i*2pi*t} — native HW sin/cos take revolutions (v_sin_f32: sin(S0*2pi))
__device__ __forceinline__ cplx sc_turn(float t) {
  return mkc(__builtin_amdgcn_cosf(t), __builtin_amdgcn_sinf(t));
}

// e^{sgn*i*pi*n^2/N1}: exact int64 mod by compile-time 2*N1, then turns
__device__ __forceinline__ cplx chirp1(float sgn, long long n) {
  long long m = (n*n) % (2*CN1);
  return sc_turn(sgn * (float)m * (1.0f/(float)(2*CN1)));
}
// e^{sgn*i*pi*n^2/N2}
__device__ __forceinline__ cplx chirp2(float sgn, long long n) {
  long long m = (n*n) % (2*CN2);
  return sc_turn(sgn * (float)m * (1.0f/(float)(2*CN2)));
}
// generic (runtime Q) — only used by the tiny BUILD dispatches
__device__ __forceinline__ cplx chirpv(float sgn, long long Q, long long n) {
  long long m = (n*n) % (2*Q);
  float ang = sgn * (0.5f*TWO_PI) * (float)m / (float)Q;
  float s, c; __sincosf(ang, &s, &c);
  return mkc(c, s);
}

__device__ __forceinline__ int brev4(int x) {
  return ((x&1)<<3) | ((x&2)<<1) | ((x&4)>>1) | ((x&8)>>3);
}
__device__ __forceinline__ int brev5(int x) {
  return (int)(__brev((unsigned)x) >> 27);
}

// ---- cross-lane xor exchange: DPP for masks 1,2,8 (VALU pipe);
//      imm ds_swizzle for 4,16 (DS pipe, no address VGPR) ----
template<int M>
__device__ __forceinline__ float shf1f(float x) {
  if constexpr (M == 1) {        // quad_perm [1,0,3,2]
    return __int_as_float(__builtin_amdgcn_mov_dpp(__float_as_int(x), 0xB1, 0xF, 0xF, true));
  } else if constexpr (M == 2) { // quad_perm [2,3,0,1]
    return __int_as_float(__builtin_amdgcn_mov_dpp(__float_as_int(x), 0x4E, 0xF, 0xF, true));
  } else if constexpr (M == 8) { // row_ror:8 == xor 8 within 16-lane row
    return __int_as_float(__builtin_amdgcn_mov_dpp(__float_as_int(x), 0x128, 0xF, 0xF, true));
  } else {                       // BitMode xor within 32 lanes
    return __int_as_float(__builtin_amdgcn_ds_swizzle(__float_as_int(x), (M << 10) | 0x1F));
  }
}
template<int M>
__device__ __forceinline__ cplx shflxT(cplx a) {
  return mkc(shf1f<M>(a.x), shf1f<M>(a.y));
}

__device__ __forceinline__ cplx h2c(__half2 h) {
  float2 f = __half22float2(h); return mkc(f.x, f.y);
}
__device__ __forceinline__ __half2 c2h(cplx c) {
  return __float22half2_rn(make_float2(c.x, c.y));
}

#define C16_1 0.9238795325f
#define C16_2 0.7071067812f
#define C16_3 0.3826834324f
__device__ __forceinline__ float c16t(int j) {
  const float C[8] = {1.f, C16_1, C16_2, C16_3, 0.f, -C16_3, -C16_2, -C16_1};
  return C[j];
}
__device__ __forceinline__ float s16t(int j) {
  const float S[8] = {0.f, C16_3, C16_2, C16_1, 1.f, C16_1, C16_2, C16_3};
  return S[j];
}

// ---- in-lane 16-point DIF, stages 2..4 (shared) ----
__device__ __forceinline__ void lane16_fwd_rest(cplx v[16], float dsg) {
  #pragma unroll
  for (int h = 0; h < 2; ++h)
    #pragma unroll
    for (int j = 0; j < 4; ++j) {
      int i0 = h*8 + j;
      cplx w = mkc(c16t(2*j), dsg * s16t(2*j));
      cplx a = v[i0], b = v[i0+4];
      v[i0] = a + b;
      v[i0+4] = cmulf(a - b, w);
    }
  #pragma unroll
  for (int q = 0; q < 4; ++q)
    #pragma unroll
    for (int j = 0; j < 2; ++j) {
      int i0 = q*4 + j;
      cplx a = v[i0], b = v[i0+2];
      cplx tt = a - b;
      v[i0] = a + b;
      v[i0+2] = (j == 0) ? tt : crot(tt, dsg);
    }
  #pragma unroll
  for (int p = 0; p < 8; ++p) {
    cplx a = v[2*p], b = v[2*p+1];
    v[2*p] = a + b;
    v[2*p+1] = a - b;
  }
}
// dense input
__device__ __forceinline__ void lane16_fwd(cplx v[16], float dsg) {
  #pragma unroll
  for (int j = 0; j < 8; ++j) {
    cplx w = mkc(c16t(j), dsg * s16t(j));
    cplx a = v[j], b = v[j+8];
    v[j] = a + b;
    v[j+8] = cmulf(a - b, w);
  }
  lane16_fwd_rest(v, dsg);
}
// v[8..15] known zero on entry (not read): stage 1 degenerates to v[j+8]=v[j]*w
__device__ __forceinline__ void lane16_fwd_h0(cplx v[16], float dsg) {
  #pragma unroll
  for (int j = 0; j < 8; ++j) {
    cplx w = mkc(c16t(j), dsg * s16t(j));
    v[j+8] = cmulf(v[j], w);
  }
  lane16_fwd_rest(v, dsg);
}

// ---- in-lane 16-point inverse-mirror ----
__device__ __forceinline__ void lane16_inv(cplx v[16], float dsg) {
  #pragma unroll
  for (int p = 0; p < 8; ++p) {
    cplx a = v[2*p], b = v[2*p+1];
    v[2*p] = a + b;
    v[2*p+1] = a - b;
  }
  #pragma unroll
  for (int q = 0; q < 4; ++q)
    #pragma unroll
    for (int j = 0; j < 2; ++j) {
      int i0 = q*4 + j;
      cplx a = v[i0], b = v[i0+2];
      cplx tb = (j == 0) ? b : crot(b, -dsg);
      v[i0] = a + tb;
      v[i0+2] = a - tb;
    }
  #pragma unroll
  for (int h = 0; h < 2; ++h)
    #pragma unroll
    for (int j = 0; j < 4; ++j) {
      int i0 = h*8 + j;
      cplx w = mkc(c16t(2*j), dsg * s16t(2*j));
      cplx a = v[i0], b = v[i0+4];
      cplx tb = cmulcf(b, w);
      v[i0] = a + tb;
      v[i0+4] = a - tb;
    }
  #pragma unroll
  for (int j = 0; j < 8; ++j) {
    cplx w = mkc(c16t(j), dsg * s16t(j));
    cplx a = v[j], b = v[j+8];
    cplx tb = cmulcf(b, w);
    v[j] = a + tb;
    v[j+8] = a - tb;
  }
}

// Per-lane cross-stage twiddles, hi-lane-selected once (low lanes get 1+0i so
// the stage body is a uniform cmul — no per-reg cndmask).
struct WSel { cplx a16, a8, a4, a2; };
__device__ __forceinline__ WSel make_wsel(int l, float dsg) {
  const cplx one = mkc(1.f, 0.f);
  WSel w;
  w.a16 = (l & 16) ? sc_turn(dsg * (1.0f/32.0f) * (float)(l & 15)) : one;
  w.a8  = (l & 8)  ? sc_turn(dsg * (1.0f/16.0f) * (float)(l & 7))  : one;
  w.a4  = (l & 4)  ? sc_turn(dsg * (1.0f/8.0f)  * (float)(l & 3))  : one;
  w.a2  = ((l & 2) && (l & 1)) ? mkc(0.f, dsg) : one;
  return w;
}

// butterfly as o + s*v (s = +-1 per stage, hoisted): one v_pk_fma each
#define XF(mask, w) {                                                          \
    const float s_ = ((l & (mask)) != 0) ? -1.f : 1.f;                         \
    _Pragma("unroll")                                                          \
    for (int r = 0; r < 16; ++r) {                                             \
      cplx o = shflxT<(mask)>(v[r]);                                           \
      v[r] = cmulf(o + s_*v[r], (w));                                          \
    } }
#define XFP(mask) {                                                            \
    const float s_ = ((l & (mask)) != 0) ? -1.f : 1.f;                         \
    _Pragma("unroll")                                                          \
    for (int r = 0; r < 16; ++r) {                                             \
      cplx o = shflxT<(mask)>(v[r]);                                           \
      v[r] = o + s_*v[r];                                                      \
    } }
#define XI(mask, w) {                                                          \
    const float s_ = ((l & (mask)) != 0) ? -1.f : 1.f;                         \
    _Pragma("unroll")                                                          \
    for (int r = 0; r < 16; ++r) {                                             \
      cplx b = cmulcf(v[r], (w));                                              \
      cplx o = shflxT<(mask)>(b);                                              \
      v[r] = o + s_*b;                                                         \
    } }
#define XIP(mask) {                                                            \
    const float s_ = ((l & (mask)) != 0) ? -1.f : 1.f;                         \
    _Pragma("unroll")                                                          \
    for (int r = 0; r < 16; ++r) {                                             \
      cplx b = v[r];                                                           \
      cplx o = shflxT<(mask)>(b);                                              \
      v[r] = o + s_*b;                                                         \
    } }

// ---- W512^{l*brev4(r)} twiddle block via binary power chain ----
// brev4 is an involution: power k applies to register brev4(k).
// 1 sc_turn + 14 cmul replaces 15 sc_turn. Static indices only (rule #20).
#define TW_APPLY_FWD(rr, wexpr) v[rr] = cmulf(v[rr], (wexpr));
#define TW_APPLY_INV(rr, wexpr) v[rr] = cmulcf(v[rr], (wexpr));
#define TW512_BODY(APPLY)                                                      \
  cplx w1 = sc_turn(dsg * INV512T * (float)l);                                 \
  cplx w2 = cmulf(w1, w1);                                                     \
  cplx w3 = cmulf(w2, w1);                                                     \
  cplx w4 = cmulf(w2, w2);                                                     \
  cplx w8 = cmulf(w4, w4);                                                     \
  cplx w12 = cmulf(w8, w4);                                                    \
  APPLY(8, w1)  APPLY(4, w2)  APPLY(12, w3) APPLY(2, w4)                       \
  APPLY(10, cmulf(w4, w1)) APPLY(6, cmulf(w4, w2)) APPLY(14, cmulf(w4, w3))    \
  APPLY(1, w8)  APPLY(9, cmulf(w8, w1)) APPLY(5, cmulf(w8, w2))                \
  APPLY(13, cmulf(w8, w3)) APPLY(3, w12) APPLY(11, cmulf(w12, w1))             \
  APPLY(7, cmulf(w12, w2)) APPLY(15, cmulf(w12, w3))

__device__ __forceinline__ void twiddle512_fwd(cplx v[16], int l, float dsg) {
  TW512_BODY(TW_APPLY_FWD)
}
__device__ __forceinline__ void twiddle512_inv(cplx v[16], int l, float dsg) {
  TW512_BODY(TW_APPLY_INV)
}

// Full 512-pt forward: input lane l reg m = x[l+32m];
// output lane l reg r = X[brev4(r) + 16*brev5(l)].
__device__ __forceinline__ void fft512_core_fwd(cplx v[16], int l, float dsg,
                                                const WSel& w) {
  twiddle512_fwd(v, l, dsg);
  XF(16, w.a16); XF(8, w.a8); XF(4, w.a4); XF(2, w.a2); XFP(1);
}
__device__ __forceinline__ void fft512_fwd(cplx v[16], int l, float dsg,
                                           const WSel& w) {
  lane16_fwd(v, dsg);
  fft512_core_fwd(v, l, dsg, w);
}
__device__ __forceinline__ void fft512_fwd_h0(cplx v[16], int l, float dsg,
                                              const WSel& w) {
  lane16_fwd_h0(v, dsg);
  fft512_core_fwd(v, l, dsg, w);
}

// Unnormalized inverse (x512) of fft512_fwd(dsg)
__device__ __forceinline__ void fft512_inv(cplx v[16], int l, float dsg,
                                           const WSel& w) {
  XIP(1); XI(2, w.a2); XI(4, w.a4); XI(8, w.a8); XI(16, w.a16);
  twiddle512_inv(v, l, dsg);
  lane16_inv(v, dsg);
}

// Storage layout of 512x512 half2 intermediates:
//   row dimension: PERMUTED — bin kf lives at row-slot rs = p(kf) where
//   p(kf) = 32*brev4(kf&15) + brev5(kf>>4); for the col-FFT register (l,r)
//   holding bin brev4(r)+16*brev5(l), rs = 32*r + l (LINEAR in reg/lane).
//   pos dimension: PAIR interleave — (rs, pos) at (rs>>1)*1024 + pos*2 + (rs&1).
//   Logical bin from slot: j(rs) = 16*brev5(rs&31) + brev4(rs>>5).

// ---------------- column pass (256 threads, 8 columns/block) ----------------
__global__ __launch_bounds__(256) void pass_col_k(
    int mode,
    const float* __restrict__ realSrc, int realLen,
    const __half2* cplxSrc,
    const __half2* __restrict__ hcIn,
    __half2* dstFull,
    __half2* __restrict__ specOut,
    float* __restrict__ realOut,
    long long Q, float csgn, int lo, int hi)
{
  // half2 tile: 8 cols * 518 = 16576 B; FINAL aliases float 8*261*4 = 8352 B
  __shared__ __align__(16) unsigned char ldsraw[8 * TS * 4];
  __half2* tile = (__half2*)ldsraw;
  const int t   = threadIdx.x;
  const int c0  = blockIdx.x * 8;
  const int ch  = blockIdx.y;
  const int l   = t & 31;
  const int ccf = t >> 5;
  const int c   = c0 + ccf;
  cplx v[16];
  WSel ws = make_wsel(l, -1.f);

  if (mode == CM_BUILD) {
    #pragma unroll
    for (int m = 0; m < 16; ++m) {
      int n = ((l + 32*m) << 9) + c;
      int np = (n <= hi) ? n : n - L1FFT;
      v[m] = (np >= lo) ? chirpv(csgn, Q, (long long)np) : mkc(0.f, 0.f);
    }
  } else if (mode == CM_REAL) {
    // input rows >= 256 are zero (realLen <= 131072) — stage rows < 256 only
    #pragma unroll
    for (int i = 0; i < 8; ++i) {
      int qq = t + 256*i;
      int cc = qq & 7, r = qq >> 3;           // r < 256
      int n = (r << 9) + c0 + cc;
      cplx val = mkc(0.f, 0.f);
      if (n < realLen) {
        float xv = realSrc[(size_t)ch * realLen + n];
        val = chirp1(-1.f, (long long)n) * xv;        // pre-chirp
      }
      tile[cc*TS + r] = c2h(val);
    }
    __syncthreads();
    #pragma unroll
    for (int m = 0; m < 8; ++m) v[m] = h2c(tile[ccf*TS + l + 32*m]);
    __syncthreads();
  } else {
    // LINEAR gather (permuted rows): uint2 = 2 half2 = 2 row-slots per thread
    const uint2* srcp = (const uint2*)(cplxSrc + (size_t)ch * L1FFT);
    #pragma unroll
    for (int i = 0; i < 8; ++i) {
      int qq = t + 256*i;
      int cc = qq & 7, rp = qq >> 3;          // rp < 256 (row-slot pair)
      uint2 val = srcp[(size_t)rp*512 + c0 + cc];
      *(uint2*)&tile[cc*TS + 2*rp] = val;
    }
    __syncthreads();
    #pragma unroll
    for (int m = 0; m < 16; ++m) v[m] = h2c(tile[ccf*TS + l + 32*m]);
    __syncthreads();
  }

  if (mode == CM_COMBINE) {
    fft512_inv(v, l, -1.f, ws);     // completes X's Bluestein conv
    #pragma unroll
    for (int m = 0; m <= 4; ++m) {  // n < 160 <=> k < MBINS
      int n = l + 32*m;
      // Hc already carries postchirp1*prechirp2*eps/CN2 (folded at EXTRACT)
      cplx H = h2c(hcIn[(size_t)ch*MBINS + c*160 + n]);
      v[m] = cmulf(v[m], H);
    }
    #pragma unroll
    for (int m = 5; m < 8; ++m) v[m] = mkc(0.f, 0.f);
  }

  if (mode <= CM_COMBINE) {         // BUILD / REAL / COMBINE: fwd FFT + store
    if (mode == CM_BUILD) fft512_fwd(v, l, -1.f, ws);
    else                  fft512_fwd_h0(v, l, -1.f, ws);  // upper half zero
    {
      // four-step twiddle w(r) = e^{-2pi i c (brev4(r)+16*brev5(l))/L}
      //                        = B^{brev4(r)} * C : B,C sc_turn + cmul chains.
      // batch k=4q..4q+3 applies to r = brev4(k); d_i *= B^4 between batches.
      cplx B1 = sc_turn(-INVLT * (float)c);
      cplx C  = sc_turn(-INVLT * (float)(c * (16*brev5(l))));
      cplx B2 = cmulf(B1, B1);
      cplx B4 = cmulf(B2, B2);
      cplx d0 = C, d1 = cmulf(C, B1), d2 = cmulf(C, B2), d3 = cmulf(d1, B2);
      #define ST4(r0,r1,r2,r3)                                                 \
        tile[ccf*TS + l + 32*(r0)] = c2h(cmulf(v[r0], d0));                    \
        tile[ccf*TS + l + 32*(r1)] = c2h(cmulf(v[r1], d1));                    \
        tile[ccf*TS + l + 32*(r2)] = c2h(cmulf(v[r2], d2));                    \
        tile[ccf*TS + l + 32*(r3)] = c2h(cmulf(v[r3], d3));
      #define DUP4()                                                           \
        d0 = cmulf(d0, B4); d1 = cmulf(d1, B4);                                \
        d2 = cmulf(d2, B4); d3 = cmulf(d3, B4);
      ST4(0, 8, 4, 12)  DUP4()
      ST4(2, 10, 6, 14) DUP4()
      ST4(1, 9, 5, 13)  DUP4()
      ST4(3, 11, 7, 15)
      #undef ST4
      #undef DUP4
    }
    __syncthreads();
    {
      uint2* dstp = (uint2*)(dstFull + (size_t)ch * L1FFT);
      #pragma unroll
      for (int i = 0; i < 8; ++i) {
        int qq = t + 256*i;
        int cc = qq & 7, rp = qq >> 3;
        dstp[(size_t)rp*512 + c0 + cc] = *(const uint2*)&tile[cc*TS + 2*rp];
      }
    }
  } else if (mode == CM_EXTRACT) {
    fft512_inv(v, l, -1.f, ws);
    #pragma unroll
    for (int m = 0; m <= 4; ++m) {
      int n = l + 32*m;
      long long k = ((long long)n << 9) + c;
      cplx cw = chirp1(-1.f, k);                 // postchirp of conv1
      float fk = (float)k;
      cplx wc = sc_turn(fk * fk * CHIRP12);      // rechirp for conv2 (N1-N2=1)
      float eps = (k == 0 || k == MBINS-1) ? 1.f : 2.f;
      float sc = eps / (float)CN2;
      cplx cw2 = cmulf(cw, wc) * sc;
      specOut[(size_t)ch*MBINS + c*160 + n] = c2h(cmulf(v[m], cw2));
    }
  } else {                          // CM_FINAL
    fft512_inv(v, l, -1.f, ws);
    float* tf = (float*)ldsraw;
    #pragma unroll
    for (int m = 0; m < 8; ++m) {
      int n = l + 32*m;
      long long nb = ((long long)n << 9) + c;
      cplx cw = chirp2(+1.f, nb);
      tf[ccf*TFS + n] = v[m].x*cw.x - v[m].y*cw.y;
    }
    __syncthreads();
    {
      int cc = t & 7, u = t >> 3;
      #pragma unroll
      for (int i = 0; i < 8; ++i) {
        int n = u + 32*i;
        realOut[(size_t)ch*XLEN + (n << 9) + c0 + cc] = tf[cc*TFS + n];
      }
    }
  }
}

// ---------------- row pass (LDS-free, 256 threads, PAIR layout) --------------
__global__ __launch_bounds__(256) void pass_row_k(
    int mode, __half2* a, const __half2* __restrict__ g)
{
  const int t = threadIdx.x;
  const int l = t & 31;
  const int w8 = t >> 5;                      // 0..7
  const int rs = blockIdx.x * 8 + w8;         // storage row-slot
  const int rp = rs >> 1, par = rs & 1;       // wave = slot pair
  const int ch = blockIdx.y;
  // logical FFT bin of this storage slot (for the four-step twiddle)
  const int j = 16*brev5(rs & 31) + brev4(rs >> 5);
  // PAIR: (rs, pos) -> rp*1024 + pos*2 + par; pos = l + 32m -> +64m
  __half2* A = a + (size_t)ch * L1FFT + (size_t)rp * 1024 + 2*l + par;
  cplx v[16];
  WSel ws = make_wsel(l, -1.f);
  #pragma unroll
  for (int m = 0; m < 16; ++m) v[m] = h2c(A[64*m]);

  if (mode == RM_CONV) {
    const __half2* G = g + (size_t)rp * 1024 + 2*l + par;
    cplx gv[16];
    #pragma unroll
    for (int m = 0; m < 16; ++m) gv[m] = h2c(G[64*m]);
    fft512_fwd(v, l, -1.f, ws);
    #pragma unroll
    for (int r = 0; r < 16; ++r) v[r] = cmulf(v[r], gv[r]);
    fft512_inv(v, l, -1.f, ws);
    // conj four-step twiddle e^{+2pi i (l+32m) j / L} = T0 * F^m, geometric
    // recurrence; 1/L folded into T0. 2 sc_turn replace 16.
    {
      cplx T = sc_turn(INVLT * (float)(l * j)) * (1.f/(float)L1FFT);
      cplx F = sc_turn(INVLT * (float)(32 * j));
      #pragma unroll
      for (int m = 0; m < 16; ++m) {
        A[64*m] = c2h(cmulf(v[m], T));
        T = cmulf(T, F);
      }
    }
  } else {
    fft512_fwd(v, l, -1.f, ws);
    #pragma unroll
    for (int r = 0; r < 16; ++r) A[64*r] = c2h(v[r]);  // state order
  }
}

__global__ void diag_ws_too_small(float* out) { out[0] = 123456.0f; }

extern "C" void kernel_launch(void* const* d_in, const int* in_sizes, int n_in,
                              void* d_out, int out_size, void* d_ws, size_t ws_size,
                              hipStream_t stream) {
  const float* x = (const float*)d_in[0];   // (32,4,131072) f32
  const float* h = (const float*)d_in[1];   // (32,4,32768)  f32
  float* out = (float*)d_out;

  const size_t fixedB   = 2ull * L1FFT * sizeof(__half2);
  const size_t perChanB = (size_t)L1FFT * sizeof(__half2) + (size_t)MBINS * sizeof(__half2);
  if (ws_size < fixedB + perChanB) {
    diag_ws_too_small<<<1, 1, 0, stream>>>(out);
    return;
  }
  int chunk = (int)((ws_size - fixedB) / perChanB);
  if (chunk > NCHAN) chunk = NCHAN;

  __half2* V1 = (__half2*)d_ws;
  __half2* W  = V1 + L1FFT;
  __half2* A  = W + L1FFT;
  __half2* Hc = A + (size_t)chunk * L1FFT;

  dim3 blk(256);
  dim3 g1(64, 1);

  // chirp-kernel spectra (channel-independent)
  pass_col_k<<<g1, blk, 0, stream>>>(CM_BUILD, nullptr, 0, nullptr, nullptr,
                                     V1, nullptr, nullptr, CN1, +1.f, -(XLEN-1), MBINS-1);
  pass_row_k<<<g1, blk, 0, stream>>>(RM_BUILD, V1, nullptr);
  pass_col_k<<<g1, blk, 0, stream>>>(CM_BUILD, nullptr, 0, nullptr, nullptr,
                                     W, nullptr, nullptr, CN2, -1.f, -(MBINS-1), XLEN-1);
  pass_row_k<<<g1, blk, 0, stream>>>(RM_BUILD, W, nullptr);

  for (int ch0 = 0; ch0 < NCHAN; ch0 += chunk) {
    int nc = NCHAN - ch0; if (nc > chunk) nc = chunk;
    dim3 gC(64, nc), gR(64, nc);
    const float* hq = h   + (size_t)ch0 * HLEN;
    const float* xq = x   + (size_t)ch0 * XLEN;
    float*       oq = out + (size_t)ch0 * XLEN;

    // H[k] -> Hc ([c][n] layout, half2, postchirp+rechirp+eps/CN2 applied)
    pass_col_k<<<gC, blk, 0, stream>>>(CM_REAL, hq, HLEN, nullptr, nullptr,
                                       A, nullptr, nullptr, CN1, 0.f, 0, 0);
    pass_row_k<<<gR, blk, 0, stream>>>(RM_CONV, A, V1);
    pass_col_k<<<gC, blk, 0, stream>>>(CM_EXTRACT, nullptr, 0, A, nullptr,
                                       nullptr, Hc, nullptr, CN1, 0.f, 0, 0);

    // X path + combine + inverse-chirp transform
    pass_col_k<<<gC, blk, 0, stream>>>(CM_REAL, xq, XLEN, nullptr, nullptr,
                                       A, nullptr, nullptr, CN1, 0.f, 0, 0);
    pass_row_k<<<gR, blk, 0, stream>>>(RM_CONV, A, V1);
    pass_col_k<<<gC, blk, 0, stream>>>(CM_COMBINE, nullptr, 0, A, Hc,
                                       A, nullptr, nullptr, CN2, 0.f, 0, 0);
    pass_row_k<<<gR, blk, 0, stream>>>(RM_CONV, A, W);
    pass_col_k<<<gC, blk, 0, stream>>>(CM_FINAL, nullptr, 0, A, nullptr,
                                       nullptr, nullptr, oq, CN2, 0.f, 0, 0);
  }
}